// Round 1
// baseline (1077.389 us; speedup 1.0000x reference)
//
#include <hip/hip_runtime.h>

#define N_ROWS 200000
#define D_IN   512
#define D_HID  2048
#define BM     128                       // rows per block (4 waves x 32 rows)
#define NBLK   ((N_ROWS + BM - 1) / BM)  // 1563
#define JT     16                        // j-tile width (hidden units per iter)
#define NJT    (D_HID / JT)              // 128

typedef short  bf16x8 __attribute__((ext_vector_type(8)));
typedef float  f32x4  __attribute__((ext_vector_type(4)));
typedef unsigned short u16x4 __attribute__((ext_vector_type(4)));

// workspace layout
#define CNT_OFS  0
#define PERM_OFS 16
#define W1_OFS   (PERM_OFS + 3 * N_ROWS * 4)   // 2400016, 16B aligned

__device__ __forceinline__ unsigned short f2bf(float f) {
  unsigned u = __builtin_bit_cast(unsigned, f);
  u += 0x7fffu + ((u >> 16) & 1u);               // round-to-nearest-even
  return (unsigned short)(u >> 16);
}

// ---------------- prep: convert 3x W1 fp32 -> bf16 ----------------
__global__ void k_convert(const float* __restrict__ w1c, const float* __restrict__ w1h,
                          const float* __restrict__ w1o, unsigned short* __restrict__ dst) {
  const int per = (D_HID * D_IN) / 4;            // 262144 float4 groups per matrix
  int i = blockIdx.x * 256 + threadIdx.x;
  if (i >= 3 * per) return;
  int t = i / per, r = i - t * per;
  const float* src = (t == 0) ? w1c : ((t == 1) ? w1h : w1o);
  f32x4 v = *(const f32x4*)(src + r * 4);
  u16x4 o;
  o[0] = f2bf(v[0]); o[1] = f2bf(v[1]); o[2] = f2bf(v[2]); o[3] = f2bf(v[3]);
  *(u16x4*)(dst + (size_t)i * 4) = o;
}

// ---------------- prep: bucket rows by atom type ----------------
__global__ void k_route(const int* __restrict__ an, int* __restrict__ cnt,
                        int* __restrict__ perm) {
  int i = blockIdx.x * 256 + threadIdx.x;
  int lane = threadIdx.x & 63;
  int t = -1;
  if (i < N_ROWS) {
    int a = an[i];
    t = (a == 6) ? 0 : ((a == 1) ? 1 : 2);
  }
#pragma unroll
  for (int tt = 0; tt < 3; ++tt) {
    unsigned long long m = __ballot(t == tt);
    if (t == tt) {
      int off = (int)__popcll(m & ((1ull << lane) - 1ull));
      int base = 0;
      if (off == 0) base = atomicAdd(&cnt[tt], (int)__popcll(m));  // one atomic per wave
      base = __shfl(base, (int)(__ffsll((long long)m) - 1), 64);
      perm[tt * N_ROWS + base + off] = i;
    }
  }
}

// ---------------- main: grouped MFMA GEMM + fused layer-2 epilogue ----------------
// Wave tile: 32 rows (A fully in regs, K=512) x 16 hidden cols per iter.
// W1 j-tile [16 x 512] bf16 double-buffered in LDS via global_load_lds,
// XOR-swizzled (pre-swizzled source) for conflict-free ds_read_b128.
__global__ __launch_bounds__(256, 2) void k_mlp(
    const float* __restrict__ x,
    const unsigned short* __restrict__ w1base,
    const int* __restrict__ perm, const int* __restrict__ cnt,
    const float* __restrict__ b1c, const float* __restrict__ b1h, const float* __restrict__ b1o,
    const float* __restrict__ w2c, const float* __restrict__ w2h, const float* __restrict__ w2o,
    const float* __restrict__ b2c, const float* __restrict__ b2h, const float* __restrict__ b2o,
    float* __restrict__ out) {
  int bid = blockIdx.x;
  int t = bid / NBLK, m = bid - t * NBLK;
  int cnt_t = cnt[t];
  int base_row = m * BM;
  if (base_row >= cnt_t) return;

  const unsigned short* w1 = w1base + (size_t)t * (D_HID * D_IN);
  const float* b1 = (t == 0) ? b1c : ((t == 1) ? b1h : b1o);
  const float* w2 = (t == 0) ? w2c : ((t == 1) ? w2h : w2o);
  const float* b2 = (t == 0) ? b2c : ((t == 1) ? b2h : b2o);
  const int* permt = perm + t * N_ROWS;

  const int tid = threadIdx.x;
  const int w = tid >> 6, lane = tid & 63;
  const int lj = lane & 15, lq = lane >> 4;

  __shared__ __align__(16) unsigned short smem[2 * JT * D_IN];  // 2 x 16 KB

  // ---- A fragments: 32 rows/wave, full K in registers (128 VGPR) ----
  int rowg[2];
#pragma unroll
  for (int rf = 0; rf < 2; ++rf) {
    int idx = base_row + w * 32 + rf * 16 + lj;
    idx = min(idx, cnt_t - 1);                   // clamp tail rows (store predicated later)
    rowg[rf] = permt[idx];
  }
  bf16x8 afrag[2][16];
#pragma unroll
  for (int rf = 0; rf < 2; ++rf) {
    const float* xr = x + (size_t)rowg[rf] * D_IN + lq * 8;
#pragma unroll
    for (int ks = 0; ks < 16; ++ks) {
      f32x4 v0 = *(const f32x4*)(xr + ks * 32);
      f32x4 v1 = *(const f32x4*)(xr + ks * 32 + 4);
      bf16x8 a;
      a[0] = (short)f2bf(v0[0]); a[1] = (short)f2bf(v0[1]);
      a[2] = (short)f2bf(v0[2]); a[3] = (short)f2bf(v0[3]);
      a[4] = (short)f2bf(v1[0]); a[5] = (short)f2bf(v1[1]);
      a[6] = (short)f2bf(v1[2]); a[7] = (short)f2bf(v1[3]);
      afrag[rf][ks] = a;
    }
  }

  // stage one W1 j-tile into LDS buffer `buf`; LDS dest is linear per wave,
  // source chunk index is XOR-swizzled so reads can swizzle identically (rule #21)
  auto stage = [&](int buf, int j0) {
#pragma unroll
    for (int c = 0; c < 4; ++c) {
      int r = w * 4 + c;                         // tile row 0..15
      const unsigned short* src = w1 + (size_t)(j0 + r) * D_IN + ((lane ^ (r & 7)) * 8);
      unsigned short* dst = &smem[buf * (JT * D_IN) + r * D_IN];  // uniform; HW adds lane*16B
      __builtin_amdgcn_global_load_lds(
          (const __attribute__((address_space(1))) unsigned int*)src,
          (__attribute__((address_space(3))) unsigned int*)dst, 16, 0, 0);
    }
  };

  stage(0, 0);
  f32x4 osum0 = {0.f, 0.f, 0.f, 0.f}, osum1 = {0.f, 0.f, 0.f, 0.f};
  const int chunk0 = lq ^ (lj & 7);
  const unsigned short* bbase = &smem[lj * D_IN];
  __syncthreads();

  for (int jt = 0; jt < NJT; ++jt) {
    int cur = jt & 1;
    if (jt + 1 < NJT) stage(cur ^ 1, (jt + 1) * JT);
    float b1v = b1[jt * JT + lj];
    float w2v = w2[jt * JT + lj];
    f32x4 acc0 = {0.f, 0.f, 0.f, 0.f}, acc1 = {0.f, 0.f, 0.f, 0.f};
    const unsigned short* bb = bbase + cur * (JT * D_IN);
#pragma unroll
    for (int ks = 0; ks < 16; ++ks) {
      bf16x8 bfrag = *(const bf16x8*)(bb + ((((ks << 2) ^ chunk0)) << 3));
      acc0 = __builtin_amdgcn_mfma_f32_16x16x32_bf16(afrag[0][ks], bfrag, acc0, 0, 0, 0);
      acc1 = __builtin_amdgcn_mfma_f32_16x16x32_bf16(afrag[1][ks], bfrag, acc1, 0, 0, 0);
    }
    // fused layer 2: out += relu(h + b1) * w2, accumulated per-lane over j
#pragma unroll
    for (int q = 0; q < 4; ++q) {
      osum0[q] += fmaxf(acc0[q] + b1v, 0.f) * w2v;
      osum1[q] += fmaxf(acc1[q] + b1v, 0.f) * w2v;
    }
    __syncthreads();
  }

  // reduce across the 16 col-lanes (C layout: col=lane&15, row=(lane>>4)*4+q)
  float b2v = b2[0];
#pragma unroll
  for (int rf = 0; rf < 2; ++rf) {
    f32x4 os = rf ? osum1 : osum0;
#pragma unroll
    for (int q = 0; q < 4; ++q) {
      float v = os[q];
      v += __shfl_xor(v, 1, 64);
      v += __shfl_xor(v, 2, 64);
      v += __shfl_xor(v, 4, 64);
      v += __shfl_xor(v, 8, 64);
      int idx = base_row + w * 32 + rf * 16 + lq * 4 + q;
      if (lj == 0 && idx < cnt_t) out[permt[idx]] = v + b2v;
    }
  }
}

extern "C" void kernel_launch(void* const* d_in, const int* in_sizes, int n_in,
                              void* d_out, int out_size, void* d_ws, size_t ws_size,
                              hipStream_t stream) {
  const float* x  = (const float*)d_in[0];
  const int* an   = (const int*)d_in[1];
  const float* w1c = (const float*)d_in[2],  *b1c = (const float*)d_in[3];
  const float* w2c = (const float*)d_in[4],  *b2c = (const float*)d_in[5];
  const float* w1h = (const float*)d_in[6],  *b1h = (const float*)d_in[7];
  const float* w2h = (const float*)d_in[8],  *b2h = (const float*)d_in[9];
  const float* w1o = (const float*)d_in[10], *b1o = (const float*)d_in[11];
  const float* w2o = (const float*)d_in[12], *b2o = (const float*)d_in[13];
  float* out = (float*)d_out;

  int* cnt  = (int*)d_ws;
  int* perm = (int*)((char*)d_ws + PERM_OFS);
  unsigned short* w1bf = (unsigned short*)((char*)d_ws + W1_OFS);

  hipMemsetAsync(d_ws, 0, 16, stream);  // zero the 3 routing counters
  k_convert<<<(3 * (D_HID * D_IN) / 4 + 255) / 256, 256, 0, stream>>>(w1c, w1h, w1o, w1bf);
  k_route<<<(N_ROWS + 255) / 256, 256, 0, stream>>>(an, cnt, perm);
  k_mlp<<<3 * NBLK, 256, 0, stream>>>(x, w1bf, perm, cnt,
                                      b1c, b1h, b1o, w2c, w2h, w2o,
                                      b2c, b2h, b2o, out);
}